// Round 9
// baseline (3869.123 us; speedup 1.0000x reference)
//
#include <hip/hip_runtime.h>
#include <hip/hip_bf16.h>

// (B,C,H,G) = (4,128,8,64); F=4096, DH=16, 127 rings.
#define Bn 4
#define Cn 128
#define Fn 4096
#define NRINGS 127
#define NWG 64

typedef short bhalf4 __attribute__((ext_vector_type(4)));
typedef float f32x4  __attribute__((ext_vector_type(4)));

// workspace offsets (float units)
#define OFF_K    1048576
#define OFF_V    2097152
#define OFF_PM   3145728   // 4 slots * 32bh * 64q * 2kv = 16384
#define OFF_PL   3162112   // 16384
#define OFF_PO   3178496   // 4 * 32 * 64 * 16 * 2 = 262144
#define OFF_VA   3440640
#define OFF_KN   3441152
#define OFF_BAR  3441664   // 16
#define OFF_FBPM 3441680   // fallback: 65536
#define OFF_FBPL 3507216   // 65536
#define OFF_FBPO 3572752   // 1048576

__device__ __forceinline__ ushort f2bf(float f) {
    __hip_bfloat16 h = __float2bfloat16(f);
    return *reinterpret_cast<ushort*>(&h);
}

__device__ __forceinline__ void ato_store(float* p, float v) {
    __hip_atomic_store(p, v, __ATOMIC_RELAXED, __HIP_MEMORY_SCOPE_AGENT);
}
__device__ __forceinline__ float2 ato_load2(float* p) {
    unsigned long long u = __hip_atomic_load((unsigned long long*)p,
                          __ATOMIC_RELAXED, __HIP_MEMORY_SCOPE_AGENT);
    float2 r;
    r.x = __uint_as_float((unsigned)u);
    r.y = __uint_as_float((unsigned)(u >> 32));
    return r;
}

// fence-free device barrier: per-wave vmcnt drain (sc1 stores already at the
// coherent point once acked) + relaxed agent atomic counter + spin.
__device__ __forceinline__ void gbar(int* bar, int target) {
    asm volatile("s_waitcnt vmcnt(0)" ::: "memory");
    __syncthreads();
    if (threadIdx.x == 0) {
        __hip_atomic_fetch_add(bar, 1, __ATOMIC_RELAXED, __HIP_MEMORY_SCOPE_AGENT);
        while (__hip_atomic_load(bar, __ATOMIC_RELAXED, __HIP_MEMORY_SCOPE_AGENT) < target)
            __builtin_amdgcn_s_sleep(4);
    }
    __syncthreads();
}

// ---------------------------------------------------------------------------
// init: Q0bf/Kbf rows [bh][col][16] bf16; Vbf transposed [bh][d][col]. Zeroes bar.
// ---------------------------------------------------------------------------
__global__ __launch_bounds__(512, 2) void initQKV(
    const float* __restrict__ x, const float* __restrict__ Wq0,
    const float* __restrict__ Wk0, const float* __restrict__ Wv0,
    ushort* __restrict__ Q0bf, ushort* __restrict__ Kbf, ushort* __restrict__ Vbf,
    int* __restrict__ bar)
{
    __shared__ float xs[Cn * 64];
    __shared__ float Wls[3 * 128 * 33];
    const int wg = blockIdx.x, t = threadIdx.x;
    if (wg == 0 && t == 0) bar[0] = 0;
    const int b = wg >> 6, n0 = (wg & 63) << 6;
    for (int idx = t; idx < Cn * 64; idx += 512) {
        int c = idx >> 6, j = idx & 63;
        xs[idx] = x[(size_t)((b << 7) + c) * 4096 + n0 + j];
    }
    const int o = t & 127, j0 = (t >> 7) << 4;
    float aq[16], ak[16], av[16];
#pragma unroll
    for (int k = 0; k < 16; ++k) { aq[k] = 0.f; ak[k] = 0.f; av[k] = 0.f; }
    for (int cc = 0; cc < 128; cc += 32) {
        __syncthreads();
        for (int idx = t; idx < 128 * 32; idx += 512) {
            int oo = idx >> 5, jj = idx & 31;
            Wls[oo * 33 + jj]                = Wq0[(oo << 7) + cc + jj];
            Wls[128 * 33 + oo * 33 + jj]     = Wk0[(oo << 7) + cc + jj];
            Wls[2 * 128 * 33 + oo * 33 + jj] = Wv0[(oo << 7) + cc + jj];
        }
        __syncthreads();
        for (int c2 = 0; c2 < 32; ++c2) {
            float wq = Wls[o * 33 + c2];
            float wk = Wls[128 * 33 + o * 33 + c2];
            float wv = Wls[2 * 128 * 33 + o * 33 + c2];
            const f32x4* xr4 = (const f32x4*)&xs[((cc + c2) << 6) + j0];
#pragma unroll
            for (int k4 = 0; k4 < 4; ++k4) {
                f32x4 xv = xr4[k4];
#pragma unroll
                for (int e = 0; e < 4; ++e) {
                    int k = (k4 << 2) + e;
                    aq[k] += wq * xv[e]; ak[k] += wk * xv[e]; av[k] += wv * xv[e];
                }
            }
        }
    }
    const int h = o >> 4, d = o & 15;
    const int bh = (b << 3) + h;
#pragma unroll
    for (int k = 0; k < 16; ++k) {
        int col = n0 + j0 + k;
        size_t qi = (size_t)(bh * 4096 + col) * 16 + d;
        Q0bf[qi] = f2bf(aq[k]);
        Kbf[qi]  = f2bf(ak[k]);
    }
    uint vv[8];
#pragma unroll
    for (int k2 = 0; k2 < 8; ++k2)
        vv[k2] = (uint)f2bf(av[2*k2]) | ((uint)f2bf(av[2*k2+1]) << 16);
    uint4* dst = (uint4*)&Vbf[(size_t)(bh * 16 + d) * 4096 + n0 + j0];
    dst[0] = make_uint4(vv[0], vv[1], vv[2], vv[3]);
    dst[1] = make_uint4(vv[4], vv[5], vv[6], vv[7]);
}

// ---------------------------------------------------------------------------
// flash for one ring over this WG's LDS-resident keys (2048). 8 waves:
// qt=w&3 (16 q), kq=w>>2 (1024 keys). Online softmax, 256-key chunks.
// Writes per-wave partials into red (LDS): [kq*64+q][18] = o[16d], m, l.
// ---------------------------------------------------------------------------
__device__ __forceinline__ void flashRing(
    int n, int t, const ushort* qs, const ushort* Kls, const ushort* Vls,
    float* red)
{
    const int w = t >> 6, lane = t & 63;
    const int qt = w & 3, kq = w >> 2;
    if (qt * 16 >= n) return;
    const int lm = lane & 15, lg = lane >> 4;
    bhalf4 qf = *(const bhalf4*)&qs[(qt * 16 + lm) * 20 + (lg << 2)];
    const int kb0 = kq << 10;
    float m = -3e38f, lsum = 0.f;
    f32x4 oacc = {0.f, 0.f, 0.f, 0.f};
    const int gb = lane & 48;

    for (int cc = 0; cc < 4; ++cc) {
        const int kbase = kb0 + (cc << 8);
        f32x4 sc[16];
#pragma unroll
        for (int kt = 0; kt < 16; ++kt) {
            bhalf4 kf = *(const bhalf4*)&Kls[(kbase + (kt << 4) + lm) * 20 + (lg << 2)];
            f32x4 z = {0.f, 0.f, 0.f, 0.f};
            sc[kt] = __builtin_amdgcn_mfma_f32_16x16x16bf16_1k(kf, qf, z, 0, 0, 0);
        }
        float mc = -3e38f;
#pragma unroll
        for (int kt = 0; kt < 16; ++kt)
            mc = fmaxf(mc, fmaxf(fmaxf(sc[kt][0], sc[kt][1]), fmaxf(sc[kt][2], sc[kt][3])));
        mc = fmaxf(mc, __shfl_xor(mc, 16));
        mc = fmaxf(mc, __shfl_xor(mc, 32));
        float mn = fmaxf(m, mc);
        float cr = __expf((m - mn) * 0.25f);   // first chunk: exp(-huge)=0
        lsum *= cr;
        // oacc reg rg belongs to query (lg<<2)+rg; cr for query q lives at lanes lm==q
#pragma unroll
        for (int rg = 0; rg < 4; ++rg) {
            float crr = __shfl(cr, gb + ((lane >> 4) << 2) + rg);
            oacc[rg] *= crr;
        }
        m = mn;
#pragma unroll
        for (int kt = 0; kt < 16; ++kt) {
            float p0 = __expf((sc[kt][0] - m) * 0.25f);
            float p1 = __expf((sc[kt][1] - m) * 0.25f);
            float p2 = __expf((sc[kt][2] - m) * 0.25f);
            float p3 = __expf((sc[kt][3] - m) * 0.25f);
            lsum += (p0 + p1) + (p2 + p3);
            bhalf4 pv;
            pv[0] = (short)f2bf(p0); pv[1] = (short)f2bf(p1);
            pv[2] = (short)f2bf(p2); pv[3] = (short)f2bf(p3);
            bhalf4 vf = *(const bhalf4*)&Vls[lm * 2056 + kbase + (kt << 4) + (lg << 2)];
            oacc = __builtin_amdgcn_mfma_f32_16x16x16bf16_1k(pv, vf, oacc, 0, 0, 0);
        }
    }
    lsum += __shfl_xor(lsum, 16);
    lsum += __shfl_xor(lsum, 32);
#pragma unroll
    for (int rg = 0; rg < 4; ++rg)
        red[((kq << 6) + (qt << 4) + (lg << 2) + rg) * 18 + lm] = oacc[rg];
    if (lg == 0) {
        red[((kq << 6) + (qt << 4) + lm) * 18 + 16] = m * 0.25f;
        red[((kq << 6) + (qt << 4) + lm) * 18 + 17] = lsum;
    }
}

// merge the two kq halves in LDS, store 1 partial per (bh,kv) via sc1 atomics.
__device__ __forceinline__ void mergeStore(
    int n, int slot, int bh, int kv, int t, const float* red,
    float* pmS, float* plS, float* poS)
{
    int q = t >> 3, sub = t & 7;
    if (q >= n) return;
    float m0 = red[q*18 + 16],        l0 = red[q*18 + 17];
    float m1 = red[(64 + q)*18 + 16], l1 = red[(64 + q)*18 + 17];
    float M = fmaxf(m0, m1);
    float e0 = __expf(m0 - M), e1 = __expf(m1 - M);
    int pmb = ((slot * 32 + bh) * 64 + q) * 2 + kv;
    if (sub == 0) {
        ato_store(&pmS[pmb], M);
        ato_store(&plS[pmb], l0 * e0 + l1 * e1);
    }
    int d0 = sub << 1;
#pragma unroll
    for (int k = 0; k < 2; ++k) {
        int dd = d0 + k;
        float o = red[q*18 + dd] * e0 + red[(64 + q)*18 + dd] * e1;
        ato_store(&poS[(((slot * 32 + bh) * 64 + q) * 16 + dd) * 2 + kv], o);
    }
}

// combine owned cols of ring (slotC) + optional LDS K/V patch.
__device__ __forceinline__ void combinePatch(
    int cnt, int slotC, int b, int h, int kv, int t,
    const int* colsC, const int* ownIdx,
    const float* __restrict__ x, const float* __restrict__ Wk0,
    const float* __restrict__ Wv0,
    float* pmS, float* plS, float* poS,
    float* __restrict__ feats, float* outc, ushort* Kls, ushort* Vls,
    bool patch)
{
    const int keyG0 = kv << 11;
    for (int base = 0; base < cnt; base += 4) {
        {
            int sl = t >> 7, c = t & 127;
            int ow = base + sl;
            if (ow < cnt) {
                int j = ownIdx[ow], col = colsC[j];
                int hh = c >> 4, dd = c & 15, bhh = (b << 3) + hh;
                int pmb = ((slotC * 32 + bhh) * 64 + j) * 2;
                float2 mm = ato_load2(&pmS[pmb]);
                float2 ll = ato_load2(&plS[pmb]);
                float2 oo = ato_load2(&poS[(((slotC * 32 + bhh) * 64 + j) * 16 + dd) * 2]);
                float M = fmaxf(mm.x, mm.y);
                float e0 = __expf(mm.x - M), e1 = __expf(mm.y - M);
                float outv = (oo.x * e0 + oo.y * e1) / (ll.x * e0 + ll.y * e1)
                           + x[(size_t)((b << 7) + c) * 4096 + col];
                outc[(sl << 7) + c] = outv;
                if (h == 0) feats[(size_t)((b << 7) + c) * 4096 + col] = outv;
            }
        }
        __syncthreads();
        if (patch) {
            int sl = t >> 7, rem = t & 127, task = rem >> 2, quarter = rem & 3;
            int ow = base + sl;
            if (ow < cnt) {
                int isV = task >> 4, dd = task & 15;
                int col = colsC[ownIdx[ow]];
                int row = (h << 4) + dd;
                const float* W = isV ? Wv0 : Wk0;
                const f32x4* W4  = (const f32x4*)&W[(row << 7) + (quarter << 5)];
                const f32x4* oc4 = (const f32x4*)&outc[(sl << 7) + (quarter << 5)];
                float acc = 0.f;
#pragma unroll
                for (int c4 = 0; c4 < 8; ++c4) {
                    f32x4 wv = W4[c4], xv = oc4[c4];
                    acc += wv[0]*xv[0] + wv[1]*xv[1] + wv[2]*xv[2] + wv[3]*xv[3];
                }
                acc += __shfl_xor(acc, 1);
                acc += __shfl_xor(acc, 2);
                if (quarter == 0) {
                    ushort bfv = f2bf(acc);
                    int colL = col - keyG0;
                    if (isV) Vls[dd * 2056 + colL] = bfv;
                    else     Kls[colL * 20 + dd]   = bfv;
                }
            }
        }
        __syncthreads();
    }
}

// ---------------------------------------------------------------------------
// Persistent cooperative kernel: 64 WGs (b,h,kv) x 512 thr, K/V LDS-resident,
// ONE fence-free barrier per ring. Partials rotate over 4 slots.
// ---------------------------------------------------------------------------
__global__ __launch_bounds__(512, 1) void ringPersist(
    const float* __restrict__ x, const float* __restrict__ Wk0,
    const float* __restrict__ Wv0, const int* __restrict__ rings,
    const int* __restrict__ rsz, const ushort* __restrict__ Q0bf,
    const ushort* __restrict__ Kbf, const ushort* __restrict__ Vbf,
    float* pmS, float* plS, float* poS,
    float* __restrict__ feats, int* bar)
{
    __shared__ ushort Kls[2048 * 20];   // 80 KB
    __shared__ ushort Vls[16 * 2056];   // 64.25 KB
    __shared__ ushort qs[64 * 20];      // 2.5 KB
    __shared__ float  fscr[128 * 18];   // red (flash) / outc (combine) alias
    __shared__ int colsC[64], colsF[64], ownIdx[32];
    __shared__ int ownCnt;
    float* red  = fscr;
    float* outc = fscr;

    const int wg = blockIdx.x, t = threadIdx.x;
    const int b = wg >> 4, h = (wg >> 1) & 7, kv = wg & 1;
    const int bh = (b << 3) + h;
    const int keyG0 = kv << 11;

    // one-time K/V stage
    for (int idx = t; idx < 2048 * 4; idx += 512) {
        int key = idx >> 2, qtr = idx & 3;
        *(uint2*)&Kls[key * 20 + (qtr << 2)] =
            *(const uint2*)&Kbf[(size_t)((bh << 12) + keyG0 + key) * 16 + (qtr << 2)];
    }
    for (int idx = t; idx < 16 * 256; idx += 512) {
        int d = idx >> 8, c8 = idx & 255;
        *(uint4*)&Vls[d * 2056 + (c8 << 3)] =
            *(const uint4*)&Vbf[(size_t)(bh * 16 + d) * 4096 + keyG0 + (c8 << 3)];
    }
    // ring 0
    {
        const int n0 = rsz[0];
        if (t < 64) colsF[t] = (t < n0) ? rings[t] : 0;
        __syncthreads();
        if (t < 256) {
            int j = t >> 2, qtr = t & 3;
            int cq = colsF[j];
            *(uint2*)&qs[j * 20 + (qtr << 2)] =
                *(const uint2*)&Q0bf[(size_t)((bh << 12) + cq) * 16 + (qtr << 2)];
        }
        __syncthreads();
        flashRing(n0, t, qs, Kls, Vls, red);
        __syncthreads();
        mergeStore(n0, 0, bh, kv, t, red, pmS, plS, poS);
    }
    // rings 1..126
    for (int r = 1; r < NRINGS; ++r) {
        const int np = rsz[r - 1], n = rsz[r];
        gbar(bar, NWG * r);
        const int slotC = (r - 1) & 3, slot = r & 3;
        if (t < 64) colsC[t] = colsF[t];
        if (t == 0) ownCnt = 0;
        __syncthreads();
        if (t < 64) colsF[t] = (t < n) ? rings[r * 64 + t] : 0;
        if (t < np) {
            int cq = colsC[t];
            if (cq >= keyG0 && cq < keyG0 + 2048)
                ownIdx[atomicAdd(&ownCnt, 1)] = t;
        }
        __syncthreads();
        combinePatch(ownCnt, slotC, b, h, kv, t, colsC, ownIdx, x, Wk0, Wv0,
                     pmS, plS, poS, feats, outc, Kls, Vls, true);
        if (t < 256) {
            int j = t >> 2, qtr = t & 3;
            int cq = colsF[j];
            *(uint2*)&qs[j * 20 + (qtr << 2)] =
                *(const uint2*)&Q0bf[(size_t)((bh << 12) + cq) * 16 + (qtr << 2)];
        }
        __syncthreads();
        flashRing(n, t, qs, Kls, Vls, red);
        __syncthreads();
        mergeStore(n, slot, bh, kv, t, red, pmS, plS, poS);
    }
    // tail: combine ring 126 (feats only)
    {
        gbar(bar, NWG * NRINGS);
        const int np = rsz[NRINGS - 1];
        const int slotC = (NRINGS - 1) & 3;
        if (t < 64) colsC[t] = colsF[t];
        if (t == 0) ownCnt = 0;
        __syncthreads();
        if (t < np) {
            int cq = colsC[t];
            if (cq >= keyG0 && cq < keyG0 + 2048)
                ownIdx[atomicAdd(&ownCnt, 1)] = t;
        }
        __syncthreads();
        combinePatch(ownCnt, slotC, b, h, kv, t, colsC, ownIdx, x, Wk0, Wv0,
                     pmS, plS, poS, feats, outc, Kls, Vls, false);
    }
}

// ---------------------------------------------------------------------------
// FALLBACK: R5-style per-ring kernel chain (proven 1781 us path).
// ---------------------------------------------------------------------------
template<bool TAIL>
__global__ __launch_bounds__(512, 2) void fusedRingFB(
    const float* __restrict__ x, const float* __restrict__ Wk0,
    const float* __restrict__ Wv0, const int* __restrict__ rings,
    const int* __restrict__ rsz, const ushort* __restrict__ Q0bf,
    ushort* __restrict__ Kbf, ushort* __restrict__ Vbf,
    float* __restrict__ pm, float* __restrict__ pl, float* __restrict__ po,
    float* __restrict__ feats, int r)
{
    __shared__ ushort Kls[512 * 24];
    __shared__ ushort Vls[16 * 520];
    __shared__ ushort Qls[64 * 24];
    __shared__ float  outc[4 * 128];
    __shared__ int colsC[64], colsF[64];
    __shared__ int ownIdx[64];
    __shared__ int ownCnt;

    const int t = threadIdx.x, wgid = blockIdx.x;
    const int b = wgid >> 6, h = (wgid >> 3) & 7, sp = wgid & 7;
    const int bh = (b << 3) + h;
    const int n  = TAIL ? 0 : rsz[r];
    const int np = (r > 0) ? rsz[r - 1] : 0;
    const int keybase = sp << 9;

    if (t < 64) colsC[t] = (r > 0 && t < np) ? rings[(r-1)*64 + t] : -1;
    else if (t < 128) { int q = t - 64; colsF[q] = (!TAIL && q < n) ? rings[r*64 + q] : 0; }
    if (t == 0) ownCnt = 0;
    __syncthreads();

    if (!TAIL) {
        {
            const uint4* src = (const uint4*)(Kbf + (size_t)((bh << 12) + keybase + t) * 16);
            uint4 a0 = src[0], a1 = src[1];
            *(uint4*)&Kls[t*24]     = a0;
            *(uint4*)&Kls[t*24 + 8] = a1;
        }
        {
            int d = t >> 5, c32 = t & 31;
            const uint4* src = (const uint4*)(Vbf + (size_t)(bh*16 + d) * 4096 + keybase + (c32 << 4));
            uint4 a0 = src[0], a1 = src[1];
            *(uint4*)&Vls[d*520 + (c32 << 4)]     = a0;
            *(uint4*)&Vls[d*520 + (c32 << 4) + 8] = a1;
        }
        if (t < 128) {
            int q = t >> 1, half = t & 1;
            int cq = colsF[q];
            uint4 qv = *(const uint4*)(Q0bf + (size_t)((bh << 12) + cq) * 16 + half * 8);
            *(uint4*)&Qls[q*24 + half*8] = qv;
        }
    }
    __syncthreads();

    if (r > 0) {
        const int bufp = (r - 1) & 1;
        if (t < np) {
            int cq = colsC[t];
            if (cq >= keybase && cq < keybase + 512) {
                int slot = atomicAdd(&ownCnt, 1);
                ownIdx[slot] = t;
            }
        }
        __syncthreads();
        const int cnt = ownCnt;
        for (int base = 0; base < cnt; base += 4) {
            {
                int slot = t >> 7, c = t & 127;
                int ow = base + slot;
                if (ow < cnt) {
                    int j = ownIdx[ow];
                    int col = colsC[j];
                    int hh = c >> 4, dd = c & 15;
                    int p0 = ((bufp << 5) + (b << 3) + hh) * 1024 + j;
                    float mstar = -1e30f;
#pragma unroll
                    for (int s2 = 0; s2 < 16; ++s2)
                        mstar = fmaxf(mstar, pm[p0 + (s2 << 6)]);
                    float lstar = 0.f, osum = 0.f;
#pragma unroll
                    for (int s2 = 0; s2 < 16; ++s2) {
                        int pi = p0 + (s2 << 6);
                        float e = __expf(pm[pi] - mstar);
                        lstar += pl[pi] * e;
                        osum  += po[(pi << 4) + dd] * e;
                    }
                    float outv = osum / lstar + x[(size_t)((b << 7) + c) * 4096 + col];
                    outc[(slot << 7) + c] = outv;
                    if (h == 0) feats[(size_t)((b << 7) + c) * 4096 + col] = outv;
                }
            }
            __syncthreads();
            if (!TAIL && t < 128) {
                int slot = t >> 5;
                int ow = base + slot;
                if (ow < cnt) {
                    int task = t & 31;
                    int isV = task >> 4, dd = task & 15;
                    int col = colsC[ownIdx[ow]];
                    const float* W = isV ? Wv0 : Wk0;
                    const float* oc = &outc[slot << 7];
                    int row = (h << 4) + dd;
                    float acc = 0.f;
                    for (int c2 = 0; c2 < Cn; ++c2)
                        acc += W[(row << 7) + c2] * oc[c2];
                    ushort bfv = f2bf(acc);
                    if (isV) {
                        Vbf[(size_t)(bh*16 + dd) * 4096 + col] = bfv;
                        Vls[dd*520 + (col - keybase)] = bfv;
                    } else {
                        Kbf[(size_t)((bh << 12) + col) * 16 + dd] = bfv;
                        Kls[(col - keybase)*24 + dd] = bfv;
                    }
                }
            }
            __syncthreads();
        }
    }
    if (TAIL) return;

    const int w = t >> 6, lane = t & 63;
    const int qt = w & 3, kh = w >> 2;
    const int buf = r & 1;
    if (qt * 16 < n) {
        const int lm = lane & 15, lg = lane >> 4;
        bhalf4 qf = *(const bhalf4*)&Qls[(qt*16 + lm)*24 + (lg << 2)];
        const int key0 = kh << 8;
        f32x4 sc[16];
#pragma unroll
        for (int kt = 0; kt < 16; ++kt) {
            bhalf4 kf = *(const bhalf4*)&Kls[(key0 + (kt << 4) + lm)*24 + (lg << 2)];
            f32x4 z = {0.f, 0.f, 0.f, 0.f};
            sc[kt] = __builtin_amdgcn_mfma_f32_16x16x16bf16_1k(kf, qf, z, 0, 0, 0);
        }
        float m = -1e30f;
#pragma unroll
        for (int kt = 0; kt < 16; ++kt)
            m = fmaxf(m, fmaxf(fmaxf(sc[kt][0], sc[kt][1]), fmaxf(sc[kt][2], sc[kt][3])));
        m = fmaxf(m, __shfl_xor(m, 16));
        m = fmaxf(m, __shfl_xor(m, 32));
        float lsum = 0.f;
        f32x4 oacc = {0.f, 0.f, 0.f, 0.f};
#pragma unroll
        for (int kt = 0; kt < 16; ++kt) {
            float p0 = __expf((sc[kt][0] - m) * 0.25f);
            float p1 = __expf((sc[kt][1] - m) * 0.25f);
            float p2 = __expf((sc[kt][2] - m) * 0.25f);
            float p3 = __expf((sc[kt][3] - m) * 0.25f);
            lsum += (p0 + p1) + (p2 + p3);
            bhalf4 pv;
            pv[0] = (short)f2bf(p0); pv[1] = (short)f2bf(p1);
            pv[2] = (short)f2bf(p2); pv[3] = (short)f2bf(p3);
            bhalf4 vf = *(const bhalf4*)&Vls[lm*520 + key0 + (kt << 4) + (lg << 2)];
            oacc = __builtin_amdgcn_mfma_f32_16x16x16bf16_1k(pv, vf, oacc, 0, 0, 0);
        }
        lsum += __shfl_xor(lsum, 16);
        lsum += __shfl_xor(lsum, 32);
        const int pb = ((((buf << 5) + bh) << 4) | ((sp << 1) + kh)) * 64;
        if (lg == 0) {
            pm[pb + qt*16 + lm] = m * 0.25f;
            pl[pb + qt*16 + lm] = lsum;
        }
#pragma unroll
        for (int reg = 0; reg < 4; ++reg)
            po[(pb + qt*16 + (lg << 2) + reg) * 16 + lm] = oacc[reg];
    }
}

// ---------------------------------------------------------------------------
// Epilogues
// ---------------------------------------------------------------------------
__global__ __launch_bounds__(128) void epi1(
    const float* __restrict__ feats, const float* __restrict__ Wv0,
    const float* __restrict__ Wk1, const int* __restrict__ rings,
    float* __restrict__ Va, float* __restrict__ Kn)
{
    int b = blockIdx.x;
    int i = threadIdx.x;
    int anchor = rings[0];
    __shared__ float la[128];
    __shared__ float kk2[128];
    la[i] = feats[(size_t)((b << 7) + i) * 4096 + anchor];
    __syncthreads();
    float va = 0.f, k1 = 0.f;
    for (int c = 0; c < 128; ++c) {
        va += Wv0[i * 128 + c] * la[c];
        k1 += Wk1[i * 128 + c] * la[c];
    }
    Va[b * 128 + i] = va;
    kk2[i] = k1 * k1;
    __syncthreads();
    float ss = 0.f;
    int hb = i & ~15;
    for (int d = 0; d < 16; ++d) ss += kk2[hb + d];
    Kn[b * 128 + i] = k1 * rsqrtf(ss + 1e-8f);
}

__global__ __launch_bounds__(256) void epi2(
    const float* __restrict__ x, const float* __restrict__ Wq1,
    const float* __restrict__ Va, const float* __restrict__ Kn,
    float* __restrict__ scores)
{
    __shared__ float Wt[128 * 132];
    __shared__ float lxT[128 * 36];
    const int bid = blockIdx.x, t = threadIdx.x;
    const int b = bid >> 7, col0 = (bid & 127) << 5;
    for (int idx = t; idx < 128 * 128; idx += 256) {
        int o = idx >> 7, c = idx & 127;
        Wt[c*132 + o] = Wq1[idx];
    }
    for (int idx = t; idx < 128 * 32; idx += 256) {
        int c = idx >> 5, col = idx & 31;
        lxT[c*36 + col] = x[(size_t)((b << 7) + c) * 4096 + col0 + col] + Va[(b << 7) + c];
    }
    __syncthreads();
    const int og = t & 31, colg = t >> 5;
    const int o0 = og << 2, cl0 = colg << 2;
    float acc[4][4];
#pragma unroll
    for (int i = 0; i < 4; ++i)
#pragma unroll
        for (int j = 0; j < 4; ++j) acc[i][j] = 0.f;
    for (int c = 0; c < 128; ++c) {
        f32x4 wv = *(const f32x4*)&Wt[c*132 + o0];
        f32x4 xv = *(const f32x4*)&lxT[c*36 + cl0];
#pragma unroll
        for (int i = 0; i < 4; ++i)
#pragma unroll
            for (int j = 0; j < 4; ++j) acc[i][j] += wv[i] * xv[j];
    }
    float kn4[4];
#pragma unroll
    for (int i = 0; i < 4; ++i) kn4[i] = Kn[(b << 7) + o0 + i];
    float res[4];
#pragma unroll
    for (int j = 0; j < 4; ++j) {
        float ss = acc[0][j]*acc[0][j] + acc[1][j]*acc[1][j]
                 + acc[2][j]*acc[2][j] + acc[3][j]*acc[3][j];
        ss += __shfl_xor(ss, 1);
        ss += __shfl_xor(ss, 2);
        float rs = rsqrtf(ss + 1e-8f);
        float mp = (acc[0][j]*kn4[0] + acc[1][j]*kn4[1]
                  + acc[2][j]*kn4[2] + acc[3][j]*kn4[3]) * rs;
#pragma unroll
        for (int msk = 1; msk <= 16; msk <<= 1) mp += __shfl_xor(mp, msk);
        res[j] = 0.5f + mp * (1.0f / 16.0f);
    }
    if (og == 0) {
#pragma unroll
        for (int j = 0; j < 4; ++j)
            scores[(b << 12) + col0 + cl0 + j] = res[j];
    }
}

// ---------------------------------------------------------------------------
// Launcher
// ---------------------------------------------------------------------------
extern "C" void kernel_launch(void* const* d_in, const int* in_sizes, int n_in,
                              void* d_out, int out_size, void* d_ws, size_t ws_size,
                              hipStream_t stream) {
    const float* x   = (const float*)d_in[0];
    const float* Wq0 = (const float*)d_in[1];
    const float* Wk0 = (const float*)d_in[2];
    const float* Wv0 = (const float*)d_in[3];
    const float* Wq1 = (const float*)d_in[4];
    const float* Wk1 = (const float*)d_in[5];
    const int*   rings = (const int*)d_in[6];
    const int*   rsz   = (const int*)d_in[7];

    float* feats  = (float*)d_out;                 // (B,C,F)
    float* scores = feats + Bn * Cn * Fn;          // (B,F)

    float*  ws   = (float*)d_ws;
    ushort* Q0bf = (ushort*)ws;
    ushort* Kbf  = (ushort*)(ws + OFF_K);
    ushort* Vbf  = (ushort*)(ws + OFF_V);
    float*  pmS  = ws + OFF_PM;
    float*  plS  = ws + OFF_PL;
    float*  poS  = ws + OFF_PO;
    float*  Va   = ws + OFF_VA;
    float*  Kn   = ws + OFF_KN;
    int*    bar  = (int*)(ws + OFF_BAR);
    float*  fpm  = ws + OFF_FBPM;
    float*  fpl  = ws + OFF_FBPL;
    float*  fpo  = ws + OFF_FBPO;

    initQKV<<<256, 512, 0, stream>>>(x, Wq0, Wk0, Wv0, Q0bf, Kbf, Vbf, bar);

    void* args[] = { (void*)&x, (void*)&Wk0, (void*)&Wv0, (void*)&rings,
                     (void*)&rsz, (void*)&Q0bf, (void*)&Kbf, (void*)&Vbf,
                     (void*)&pmS, (void*)&plS, (void*)&poS,
                     (void*)&feats, (void*)&bar };
    hipError_t le = hipLaunchCooperativeKernel((void*)ringPersist, dim3(NWG),
                                               dim3(512), args, 0, stream);
    if (le != hipSuccess) {
        for (int r = 0; r < NRINGS; ++r) {
            fusedRingFB<false><<<256, 512, 0, stream>>>(
                x, Wk0, Wv0, rings, rsz, Q0bf, Kbf, Vbf, fpm, fpl, fpo, feats, r);
        }
        fusedRingFB<true><<<256, 512, 0, stream>>>(
            x, Wk0, Wv0, rings, rsz, Q0bf, Kbf, Vbf, fpm, fpl, fpo, feats, NRINGS);
    }

    epi1<<<Bn, 128, 0, stream>>>(feats, Wv0, Wk1, rings, Va, Kn);
    epi2<<<512, 256, 0, stream>>>(x, Wq1, Va, Kn, scores);
}

// Round 11
// 1985.336 us; speedup vs baseline: 1.9489x; 1.9489x over previous
//
#include <hip/hip_runtime.h>
#include <hip/hip_bf16.h>

// (B,C,H,G) = (4,128,8,64); F=4096, DH=16, 127 rings.
#define Bn 4
#define Cn 128
#define Fn 4096
#define NRINGS 127

typedef short bhalf4 __attribute__((ext_vector_type(4)));
typedef float f32x4  __attribute__((ext_vector_type(4)));

// workspace offsets (float-slot units)
#define OFF_K   1048576
#define OFF_V   2097152
#define OFF_PM  3145728   // 2 buf * 32 bh * 64 q * 16 sl = 65536
#define OFF_PL  3211264   // 65536
#define OFF_PO  3276800   // 2 * 32 * 64 * 16 d * 16 sl = 1048576
#define OFF_VA  4325376
#define OFF_KN  4325888

__device__ __forceinline__ ushort f2bf(float f) {
    __hip_bfloat16 h = __float2bfloat16(f);
    return *reinterpret_cast<ushort*>(&h);
}

// ---------------------------------------------------------------------------
// init: Q0bf/Kbf rows [bh][col][16] bf16; Vbf transposed [bh][d][col] bf16.
// W staged in LDS (+1-padded) per 32-c chunk: coalesced global, 2-way banks.
// ---------------------------------------------------------------------------
__global__ __launch_bounds__(512, 2) void initQKV(
    const float* __restrict__ x, const float* __restrict__ Wq0,
    const float* __restrict__ Wk0, const float* __restrict__ Wv0,
    ushort* __restrict__ Q0bf, ushort* __restrict__ Kbf, ushort* __restrict__ Vbf)
{
    __shared__ float xs[Cn * 64];
    __shared__ float Wls[3 * 128 * 33];
    const int wg = blockIdx.x, t = threadIdx.x;
    const int b = wg >> 6, n0 = (wg & 63) << 6;
    for (int idx = t; idx < Cn * 64; idx += 512) {
        int c = idx >> 6, j = idx & 63;
        xs[idx] = x[(size_t)((b << 7) + c) * 4096 + n0 + j];
    }
    const int o = t & 127, j0 = (t >> 7) << 4;
    float aq[16], ak[16], av[16];
#pragma unroll
    for (int k = 0; k < 16; ++k) { aq[k] = 0.f; ak[k] = 0.f; av[k] = 0.f; }
    for (int cc = 0; cc < 128; cc += 32) {
        __syncthreads();   // xs ready (first iter) / Wls reuse safe (later)
        for (int idx = t; idx < 128 * 32; idx += 512) {
            int oo = idx >> 5, jj = idx & 31;
            Wls[oo * 33 + jj]                = Wq0[(oo << 7) + cc + jj];
            Wls[128 * 33 + oo * 33 + jj]     = Wk0[(oo << 7) + cc + jj];
            Wls[2 * 128 * 33 + oo * 33 + jj] = Wv0[(oo << 7) + cc + jj];
        }
        __syncthreads();
        for (int c2 = 0; c2 < 32; ++c2) {
            float wq = Wls[o * 33 + c2];
            float wk = Wls[128 * 33 + o * 33 + c2];
            float wv = Wls[2 * 128 * 33 + o * 33 + c2];
            const f32x4* xr4 = (const f32x4*)&xs[((cc + c2) << 6) + j0];
#pragma unroll
            for (int k4 = 0; k4 < 4; ++k4) {
                f32x4 xv = xr4[k4];
#pragma unroll
                for (int e = 0; e < 4; ++e) {
                    int k = (k4 << 2) + e;
                    aq[k] += wq * xv[e]; ak[k] += wk * xv[e]; av[k] += wv * xv[e];
                }
            }
        }
    }
    const int h = o >> 4, d = o & 15;
    const int bh = (b << 3) + h;
#pragma unroll
    for (int k = 0; k < 16; ++k) {
        int col = n0 + j0 + k;
        size_t qi = (size_t)(bh * 4096 + col) * 16 + d;
        Q0bf[qi] = f2bf(aq[k]);
        Kbf[qi]  = f2bf(ak[k]);
    }
    uint vv[8];
#pragma unroll
    for (int k2 = 0; k2 < 8; ++k2)
        vv[k2] = (uint)f2bf(av[2*k2]) | ((uint)f2bf(av[2*k2+1]) << 16);
    uint4* dst = (uint4*)&Vbf[(size_t)(bh * 16 + d) * 4096 + n0 + j0];
    dst[0] = make_uint4(vv[0], vv[1], vv[2], vv[3]);
    dst[1] = make_uint4(vv[4], vv[5], vv[6], vv[7]);
}

// ---------------------------------------------------------------------------
// Fused per-ring kernel (R5 structure). WG (b,h,sp of 512 keys), 512 thr.
//   1) stage bf16 K rows (48B LDS rows) + V^T rows + ring-r Q into LDS
//   2) combine ring r-1: partials [bh][q][sl] / [bh][q][d][sl] ->
//      contiguous f32x4 reads; write feats (h==0); GEMV own-h K/V rows ->
//      LDS patch + global bf16
//   3) MFMA flash ring r; partial stores slice-innermost.
//      QK^T output: col(lm)=query. PV output: row((lg<<2)+reg)=query, col(lm)=d.
// ---------------------------------------------------------------------------
template<bool TAIL>
__global__ __launch_bounds__(512, 2) void fusedRing(
    const float* __restrict__ x, const float* __restrict__ Wk0,
    const float* __restrict__ Wv0, const int* __restrict__ rings,
    const int* __restrict__ rsz, const ushort* __restrict__ Q0bf,
    ushort* __restrict__ Kbf, ushort* __restrict__ Vbf,
    float* __restrict__ pm, float* __restrict__ pl, float* __restrict__ po,
    float* __restrict__ feats, int r)
{
    __shared__ ushort Kls[512 * 24];   // 24 KB, rows 48B (2-way banks)
    __shared__ ushort Vls[16 * 520];   // 16.3 KB, V^T rows, stride 1040B
    __shared__ ushort Qls[64 * 24];    // 3 KB
    __shared__ float  outc[4 * 128];
    __shared__ int colsC[64], colsF[64];
    __shared__ int ownIdx[64];
    __shared__ int ownCnt;

    const int t = threadIdx.x, wgid = blockIdx.x;
    const int b = wgid >> 6, h = (wgid >> 3) & 7, sp = wgid & 7;
    const int bh = (b << 3) + h;
    const int n  = TAIL ? 0 : rsz[r];
    const int np = (r > 0) ? rsz[r - 1] : 0;
    const int keybase = sp << 9;

    if (t < 64) colsC[t] = (r > 0 && t < np) ? rings[(r-1)*64 + t] : -1;
    else if (t < 128) { int q = t - 64; colsF[q] = (!TAIL && q < n) ? rings[r*64 + q] : 0; }
    if (t == 0) ownCnt = 0;
    __syncthreads();

    // ---------------- 1) stage ----------------
    if (!TAIL) {
        {   // K rows: thread = key
            const uint4* src = (const uint4*)(Kbf + (size_t)((bh << 12) + keybase + t) * 16);
            uint4 a0 = src[0], a1 = src[1];
            *(uint4*)&Kls[t*24]     = a0;
            *(uint4*)&Kls[t*24 + 8] = a1;
        }
        {   // V^T rows: d = t>>5, 16-key chunk = t&31
            int d = t >> 5, c32 = t & 31;
            const uint4* src = (const uint4*)(Vbf + (size_t)(bh*16 + d) * 4096 + keybase + (c32 << 4));
            uint4 a0 = src[0], a1 = src[1];
            *(uint4*)&Vls[d*520 + (c32 << 4)]     = a0;
            *(uint4*)&Vls[d*520 + (c32 << 4) + 8] = a1;
        }
        if (t < 128) {  // Q rows (ring-r cols)
            int q = t >> 1, half = t & 1;
            int cq = colsF[q];
            uint4 qv = *(const uint4*)(Q0bf + (size_t)((bh << 12) + cq) * 16 + half * 8);
            *(uint4*)&Qls[q*24 + half*8] = qv;
        }
    }
    __syncthreads();

    // ---------------- 2) combine ring r-1 ----------------
    if (r > 0) {
        const int bufp = (r - 1) & 1;
        if (t < np) {
            int cq = colsC[t];
            if (cq >= keybase && cq < keybase + 512) {
                int slot = atomicAdd(&ownCnt, 1);
                ownIdx[slot] = t;
            }
        }
        __syncthreads();
        const int cnt = ownCnt;
        for (int base = 0; base < cnt; base += 4) {
            {
                int slot = t >> 7, c = t & 127;
                int ow = base + slot;
                if (ow < cnt) {
                    int j = ownIdx[ow];
                    int col = colsC[j];
                    int hh = c >> 4, dd = c & 15;
                    int bhh = (b << 3) + hh;
                    int qb = ((((bufp << 5) + bhh) << 6) + j) << 4;   // pm/pl base
                    f32x4 m0 = *(const f32x4*)&pm[qb];
                    f32x4 m1 = *(const f32x4*)&pm[qb + 4];
                    f32x4 m2 = *(const f32x4*)&pm[qb + 8];
                    f32x4 m3 = *(const f32x4*)&pm[qb + 12];
                    float mstar = fmaxf(
                        fmaxf(fmaxf(fmaxf(m0[0],m0[1]),fmaxf(m0[2],m0[3])),
                              fmaxf(fmaxf(m1[0],m1[1]),fmaxf(m1[2],m1[3]))),
                        fmaxf(fmaxf(fmaxf(m2[0],m2[1]),fmaxf(m2[2],m2[3])),
                              fmaxf(fmaxf(m3[0],m3[1]),fmaxf(m3[2],m3[3]))));
                    f32x4 l0 = *(const f32x4*)&pl[qb];
                    f32x4 l1 = *(const f32x4*)&pl[qb + 4];
                    f32x4 l2 = *(const f32x4*)&pl[qb + 8];
                    f32x4 l3 = *(const f32x4*)&pl[qb + 12];
                    int pob = (qb + dd) << 4;                          // po base
                    f32x4 o0 = *(const f32x4*)&po[pob];
                    f32x4 o1 = *(const f32x4*)&po[pob + 4];
                    f32x4 o2 = *(const f32x4*)&po[pob + 8];
                    f32x4 o3 = *(const f32x4*)&po[pob + 12];
                    float lst = 0.f, osum = 0.f;
#pragma unroll
                    for (int s2 = 0; s2 < 4; ++s2) {
                        float e0 = __expf(m0[s2] - mstar);
                        lst += l0[s2] * e0; osum += o0[s2] * e0;
                        float e1 = __expf(m1[s2] - mstar);
                        lst += l1[s2] * e1; osum += o1[s2] * e1;
                        float e2 = __expf(m2[s2] - mstar);
                        lst += l2[s2] * e2; osum += o2[s2] * e2;
                        float e3 = __expf(m3[s2] - mstar);
                        lst += l3[s2] * e3; osum += o3[s2] * e3;
                    }
                    float outv = osum / lst + x[(size_t)((b << 7) + c) * 4096 + col];
                    outc[(slot << 7) + c] = outv;
                    if (h == 0) feats[(size_t)((b << 7) + c) * 4096 + col] = outv;
                }
            }
            __syncthreads();
            if (!TAIL && t < 128) {
                int slot = t >> 5;
                int ow = base + slot;
                if (ow < cnt) {
                    int task = t & 31;
                    int isV = task >> 4, dd = task & 15;
                    int col = colsC[ownIdx[ow]];
                    const float* W = isV ? Wv0 : Wk0;
                    const float* oc = &outc[slot << 7];
                    int row = (h << 4) + dd;
                    float acc = 0.f;
                    for (int c2 = 0; c2 < Cn; ++c2)
                        acc += W[(row << 7) + c2] * oc[c2];
                    ushort bfv = f2bf(acc);
                    if (isV) {
                        Vbf[(size_t)(bh*16 + dd) * 4096 + col] = bfv;
                        Vls[dd*520 + (col - keybase)] = bfv;
                    } else {
                        Kbf[(size_t)((bh << 12) + col) * 16 + dd] = bfv;
                        Kls[(col - keybase)*24 + dd] = bfv;
                    }
                }
            }
            __syncthreads();
        }
    }
    if (TAIL) return;

    // ---------------- 3) MFMA flash ring r ----------------
    const int w = t >> 6, lane = t & 63;
    const int qt = w & 3, kh = w >> 2;
    const int buf = r & 1;
    if (qt * 16 < n) {
        const int lm = lane & 15, lg = lane >> 4;
        bhalf4 qf = *(const bhalf4*)&Qls[(qt*16 + lm)*24 + (lg << 2)];
        const int key0 = kh << 8;
        f32x4 sc[16];
#pragma unroll
        for (int kt = 0; kt < 16; ++kt) {
            bhalf4 kf = *(const bhalf4*)&Kls[(key0 + (kt << 4) + lm)*24 + (lg << 2)];
            f32x4 z = {0.f, 0.f, 0.f, 0.f};
            sc[kt] = __builtin_amdgcn_mfma_f32_16x16x16bf16_1k(kf, qf, z, 0, 0, 0);
        }
        float m = -1e30f;
#pragma unroll
        for (int kt = 0; kt < 16; ++kt)
            m = fmaxf(m, fmaxf(fmaxf(sc[kt][0], sc[kt][1]), fmaxf(sc[kt][2], sc[kt][3])));
        m = fmaxf(m, __shfl_xor(m, 16));
        m = fmaxf(m, __shfl_xor(m, 32));
        float lsum = 0.f;
        f32x4 oacc = {0.f, 0.f, 0.f, 0.f};
#pragma unroll
        for (int kt = 0; kt < 16; ++kt) {
            float p0 = __expf((sc[kt][0] - m) * 0.25f);
            float p1 = __expf((sc[kt][1] - m) * 0.25f);
            float p2 = __expf((sc[kt][2] - m) * 0.25f);
            float p3 = __expf((sc[kt][3] - m) * 0.25f);
            lsum += (p0 + p1) + (p2 + p3);
            bhalf4 pv;
            pv[0] = (short)f2bf(p0); pv[1] = (short)f2bf(p1);
            pv[2] = (short)f2bf(p2); pv[3] = (short)f2bf(p3);
            bhalf4 vf = *(const bhalf4*)&Vls[lm*520 + key0 + (kt << 4) + (lg << 2)];
            oacc = __builtin_amdgcn_mfma_f32_16x16x16bf16_1k(pv, vf, oacc, 0, 0, 0);
        }
        lsum += __shfl_xor(lsum, 16);
        lsum += __shfl_xor(lsum, 32);
        // slice-innermost partial stores: [buf][bh][q][sl] and [buf][bh][q][d][sl]
        const int sl = (sp << 1) + kh;
        const int qbase = (((buf << 5) + bh) << 6) + qt * 16;
        if (lg == 0) {
            pm[((qbase + lm) << 4) + sl] = m * 0.25f;   // QK^T: query = lm
            pl[((qbase + lm) << 4) + sl] = lsum;
        }
#pragma unroll
        for (int reg = 0; reg < 4; ++reg) {
            int q = qbase + (lg << 2) + reg;            // PV: query = (lg<<2)+reg
            po[(((q << 4) + lm) << 4) + sl] = oacc[reg];  //     d = lm
        }
    }
}

// ---------------------------------------------------------------------------
// Epilogue 1: Va = Wv0@anchor_feats, Kn = head-normalize(Wk1@anchor_feats)
// ---------------------------------------------------------------------------
__global__ __launch_bounds__(128) void epi1(
    const float* __restrict__ feats, const float* __restrict__ Wv0,
    const float* __restrict__ Wk1, const int* __restrict__ rings,
    float* __restrict__ Va, float* __restrict__ Kn)
{
    int b = blockIdx.x;
    int i = threadIdx.x;
    int anchor = rings[0];
    __shared__ float la[128];
    __shared__ float kk2[128];
    la[i] = feats[(size_t)((b << 7) + i) * 4096 + anchor];
    __syncthreads();
    float va = 0.f, k1 = 0.f;
    for (int c = 0; c < 128; ++c) {
        va += Wv0[i * 128 + c] * la[c];
        k1 += Wk1[i * 128 + c] * la[c];
    }
    Va[b * 128 + i] = va;
    kk2[i] = k1 * k1;
    __syncthreads();
    float ss = 0.f;
    int hb = i & ~15;
    for (int d = 0; d < 16; ++d) ss += kk2[hb + d];
    Kn[b * 128 + i] = k1 * rsqrtf(ss + 1e-8f);
}

// ---------------------------------------------------------------------------
// Epilogue 2: reg-tiled. Block = 32 cols, 256 thr; W^T staged in LDS once.
// ---------------------------------------------------------------------------
__global__ __launch_bounds__(256) void epi2(
    const float* __restrict__ x, const float* __restrict__ Wq1,
    const float* __restrict__ Va, const float* __restrict__ Kn,
    float* __restrict__ scores)
{
    __shared__ float Wt[128 * 132];
    __shared__ float lxT[128 * 36];
    const int bid = blockIdx.x, t = threadIdx.x;
    const int b = bid >> 7, col0 = (bid & 127) << 5;
    for (int idx = t; idx < 128 * 128; idx += 256) {
        int o = idx >> 7, c = idx & 127;
        Wt[c*132 + o] = Wq1[idx];
    }
    for (int idx = t; idx < 128 * 32; idx += 256) {
        int c = idx >> 5, col = idx & 31;
        lxT[c*36 + col] = x[(size_t)((b << 7) + c) * 4096 + col0 + col] + Va[(b << 7) + c];
    }
    __syncthreads();
    const int og = t & 31, colg = t >> 5;
    const int o0 = og << 2, cl0 = colg << 2;
    float acc[4][4];
#pragma unroll
    for (int i = 0; i < 4; ++i)
#pragma unroll
        for (int j = 0; j < 4; ++j) acc[i][j] = 0.f;
    for (int c = 0; c < 128; ++c) {
        f32x4 wv = *(const f32x4*)&Wt[c*132 + o0];
        f32x4 xv = *(const f32x4*)&lxT[c*36 + cl0];
#pragma unroll
        for (int i = 0; i < 4; ++i)
#pragma unroll
            for (int j = 0; j < 4; ++j) acc[i][j] += wv[i] * xv[j];
    }
    float kn4[4];
#pragma unroll
    for (int i = 0; i < 4; ++i) kn4[i] = Kn[(b << 7) + o0 + i];
    float res[4];
#pragma unroll
    for (int j = 0; j < 4; ++j) {
        float ss = acc[0][j]*acc[0][j] + acc[1][j]*acc[1][j]
                 + acc[2][j]*acc[2][j] + acc[3][j]*acc[3][j];
        ss += __shfl_xor(ss, 1);
        ss += __shfl_xor(ss, 2);
        float rs = rsqrtf(ss + 1e-8f);
        float mp = (acc[0][j]*kn4[0] + acc[1][j]*kn4[1]
                  + acc[2][j]*kn4[2] + acc[3][j]*kn4[3]) * rs;
#pragma unroll
        for (int msk = 1; msk <= 16; msk <<= 1) mp += __shfl_xor(mp, msk);
        res[j] = 0.5f + mp * (1.0f / 16.0f);
    }
    if (og == 0) {
#pragma unroll
        for (int j = 0; j < 4; ++j)
            scores[(b << 12) + col0 + cl0 + j] = res[j];
    }
}

// ---------------------------------------------------------------------------
// Launcher: 1 init + 127 rings + 1 tail + 2 epilogues = 131 launches.
// ---------------------------------------------------------------------------
extern "C" void kernel_launch(void* const* d_in, const int* in_sizes, int n_in,
                              void* d_out, int out_size, void* d_ws, size_t ws_size,
                              hipStream_t stream) {
    const float* x   = (const float*)d_in[0];
    const float* Wq0 = (const float*)d_in[1];
    const float* Wk0 = (const float*)d_in[2];
    const float* Wv0 = (const float*)d_in[3];
    const float* Wq1 = (const float*)d_in[4];
    const float* Wk1 = (const float*)d_in[5];
    const int*   rings = (const int*)d_in[6];
    const int*   rsz   = (const int*)d_in[7];

    float* feats  = (float*)d_out;                 // (B,C,F)
    float* scores = feats + Bn * Cn * Fn;          // (B,F)

    float*  ws   = (float*)d_ws;
    ushort* Q0bf = (ushort*)ws;
    ushort* Kbf  = (ushort*)(ws + OFF_K);
    ushort* Vbf  = (ushort*)(ws + OFF_V);
    float*  pm   = ws + OFF_PM;
    float*  pl   = ws + OFF_PL;
    float*  po   = ws + OFF_PO;
    float*  Va   = ws + OFF_VA;
    float*  Kn   = ws + OFF_KN;

    initQKV<<<256, 512, 0, stream>>>(x, Wq0, Wk0, Wv0, Q0bf, Kbf, Vbf);

    for (int r = 0; r < NRINGS; ++r) {
        fusedRing<false><<<256, 512, 0, stream>>>(
            x, Wk0, Wv0, rings, rsz, Q0bf, Kbf, Vbf, pm, pl, po, feats, r);
    }
    fusedRing<true><<<256, 512, 0, stream>>>(
        x, Wk0, Wv0, rings, rsz, Q0bf, Kbf, Vbf, pm, pl, po, feats, NRINGS);

    epi1<<<Bn, 128, 0, stream>>>(feats, Wv0, Wk1, rings, Va, Kn);
    epi2<<<512, 256, 0, stream>>>(x, Wq1, Va, Kn, scores);
}

// Round 12
// 1735.335 us; speedup vs baseline: 2.2296x; 1.1441x over previous
//
#include <hip/hip_runtime.h>
#include <hip/hip_bf16.h>

// (B,C,H,G) = (4,128,8,64); F=4096, DH=16, 127 rings.
#define Bn 4
#define Cn 128
#define Fn 4096
#define NRINGS 127

typedef short bhalf4 __attribute__((ext_vector_type(4)));
typedef float f32x4  __attribute__((ext_vector_type(4)));

// workspace offsets (float-slot units)
#define OFF_K   1048576
#define OFF_V   2097152
#define OFF_PM  3145728   // 2 buf * 32 bh * 16 sl * 64 q = 65536
#define OFF_PL  3211264   // 65536
#define OFF_PO  3276800   // * 16 d = 1048576
#define OFF_VA  4325376
#define OFF_KN  4325888

__device__ __forceinline__ ushort f2bf(float f) {
    __hip_bfloat16 h = __float2bfloat16(f);
    return *reinterpret_cast<ushort*>(&h);
}

// ---------------------------------------------------------------------------
// init (R11 version, 47 us): Q0bf/Kbf rows [bh][col][16] bf16; Vbf transposed
// [bh][d][col] bf16. W staged in LDS (+1-padded) per 32-c chunk.
// ---------------------------------------------------------------------------
__global__ __launch_bounds__(512, 2) void initQKV(
    const float* __restrict__ x, const float* __restrict__ Wq0,
    const float* __restrict__ Wk0, const float* __restrict__ Wv0,
    ushort* __restrict__ Q0bf, ushort* __restrict__ Kbf, ushort* __restrict__ Vbf)
{
    __shared__ float xs[Cn * 64];
    __shared__ float Wls[3 * 128 * 33];
    const int wg = blockIdx.x, t = threadIdx.x;
    const int b = wg >> 6, n0 = (wg & 63) << 6;
    for (int idx = t; idx < Cn * 64; idx += 512) {
        int c = idx >> 6, j = idx & 63;
        xs[idx] = x[(size_t)((b << 7) + c) * 4096 + n0 + j];
    }
    const int o = t & 127, j0 = (t >> 7) << 4;
    float aq[16], ak[16], av[16];
#pragma unroll
    for (int k = 0; k < 16; ++k) { aq[k] = 0.f; ak[k] = 0.f; av[k] = 0.f; }
    for (int cc = 0; cc < 128; cc += 32) {
        __syncthreads();   // xs ready (first iter) / Wls reuse safe (later)
        for (int idx = t; idx < 128 * 32; idx += 512) {
            int oo = idx >> 5, jj = idx & 31;
            Wls[oo * 33 + jj]                = Wq0[(oo << 7) + cc + jj];
            Wls[128 * 33 + oo * 33 + jj]     = Wk0[(oo << 7) + cc + jj];
            Wls[2 * 128 * 33 + oo * 33 + jj] = Wv0[(oo << 7) + cc + jj];
        }
        __syncthreads();
        for (int c2 = 0; c2 < 32; ++c2) {
            float wq = Wls[o * 33 + c2];
            float wk = Wls[128 * 33 + o * 33 + c2];
            float wv = Wls[2 * 128 * 33 + o * 33 + c2];
            const f32x4* xr4 = (const f32x4*)&xs[((cc + c2) << 6) + j0];
#pragma unroll
            for (int k4 = 0; k4 < 4; ++k4) {
                f32x4 xv = xr4[k4];
#pragma unroll
                for (int e = 0; e < 4; ++e) {
                    int k = (k4 << 2) + e;
                    aq[k] += wq * xv[e]; ak[k] += wk * xv[e]; av[k] += wv * xv[e];
                }
            }
        }
    }
    const int h = o >> 4, d = o & 15;
    const int bh = (b << 3) + h;
#pragma unroll
    for (int k = 0; k < 16; ++k) {
        int col = n0 + j0 + k;
        size_t qi = (size_t)(bh * 4096 + col) * 16 + d;
        Q0bf[qi] = f2bf(aq[k]);
        Kbf[qi]  = f2bf(ak[k]);
    }
    uint vv[8];
#pragma unroll
    for (int k2 = 0; k2 < 8; ++k2)
        vv[k2] = (uint)f2bf(av[2*k2]) | ((uint)f2bf(av[2*k2+1]) << 16);
    uint4* dst = (uint4*)&Vbf[(size_t)(bh * 16 + d) * 4096 + n0 + j0];
    dst[0] = make_uint4(vv[0], vv[1], vv[2], vv[3]);
    dst[1] = make_uint4(vv[4], vv[5], vv[6], vv[7]);
}

// ---------------------------------------------------------------------------
// Fused per-ring kernel — EXACT R5 structure (proven 12.2 us/ring).
// WG (b,h,sp of 512 keys), 512 thr = 8 waves.
//   1) stage bf16 K rows (48B LDS rows) + V^T rows + ring-r Q into LDS
//   2) combine ring r-1 (16 slice-partials, R5 layout), write feats (h==0),
//      GEMV own-h K/V rows -> LDS patch + global bf16
//   3) MFMA flash ring r; coalesced partial stores (R5 layout)
// ---------------------------------------------------------------------------
template<bool TAIL>
__global__ __launch_bounds__(512, 2) void fusedRing(
    const float* __restrict__ x, const float* __restrict__ Wk0,
    const float* __restrict__ Wv0, const int* __restrict__ rings,
    const int* __restrict__ rsz, const ushort* __restrict__ Q0bf,
    ushort* __restrict__ Kbf, ushort* __restrict__ Vbf,
    float* __restrict__ pm, float* __restrict__ pl, float* __restrict__ po,
    float* __restrict__ feats, int r)
{
    __shared__ ushort Kls[512 * 24];   // 24 KB, rows 48B (2-way banks)
    __shared__ ushort Vls[16 * 520];   // 16.3 KB, V^T rows, stride 1040B
    __shared__ ushort Qls[64 * 24];    // 3 KB
    __shared__ float  outc[4 * 128];
    __shared__ int colsC[64], colsF[64];
    __shared__ int ownIdx[64];
    __shared__ int ownCnt;

    const int t = threadIdx.x, wgid = blockIdx.x;
    const int b = wgid >> 6, h = (wgid >> 3) & 7, sp = wgid & 7;
    const int bh = (b << 3) + h;
    const int n  = TAIL ? 0 : rsz[r];
    const int np = (r > 0) ? rsz[r - 1] : 0;
    const int keybase = sp << 9;

    if (t < 64) colsC[t] = (r > 0 && t < np) ? rings[(r-1)*64 + t] : -1;
    else if (t < 128) { int q = t - 64; colsF[q] = (!TAIL && q < n) ? rings[r*64 + q] : 0; }
    if (t == 0) ownCnt = 0;
    __syncthreads();

    // ---------------- 1) stage ----------------
    if (!TAIL) {
        {   // K rows: thread = key
            const uint4* src = (const uint4*)(Kbf + (size_t)((bh << 12) + keybase + t) * 16);
            uint4 a0 = src[0], a1 = src[1];
            *(uint4*)&Kls[t*24]     = a0;
            *(uint4*)&Kls[t*24 + 8] = a1;
        }
        {   // V^T rows: d = t>>5, 16-key chunk = t&31
            int d = t >> 5, c32 = t & 31;
            const uint4* src = (const uint4*)(Vbf + (size_t)(bh*16 + d) * 4096 + keybase + (c32 << 4));
            uint4 a0 = src[0], a1 = src[1];
            *(uint4*)&Vls[d*520 + (c32 << 4)]     = a0;
            *(uint4*)&Vls[d*520 + (c32 << 4) + 8] = a1;
        }
        if (t < 128) {  // Q rows (ring-r cols)
            int q = t >> 1, half = t & 1;
            int cq = colsF[q];
            uint4 qv = *(const uint4*)(Q0bf + (size_t)((bh << 12) + cq) * 16 + half * 8);
            *(uint4*)&Qls[q*24 + half*8] = qv;
        }
    }
    __syncthreads();

    // ---------------- 2) combine ring r-1 ----------------
    if (r > 0) {
        const int bufp = (r - 1) & 1;
        if (t < np) {
            int cq = colsC[t];
            if (cq >= keybase && cq < keybase + 512) {
                int slot = atomicAdd(&ownCnt, 1);
                ownIdx[slot] = t;
            }
        }
        __syncthreads();
        const int cnt = ownCnt;
        for (int base = 0; base < cnt; base += 4) {
            {
                int slot = t >> 7, c = t & 127;
                int ow = base + slot;
                if (ow < cnt) {
                    int j = ownIdx[ow];
                    int col = colsC[j];
                    int hh = c >> 4, dd = c & 15;
                    int p0 = ((bufp << 5) + (b << 3) + hh) * 1024 + j;
                    float mstar = -1e30f;
#pragma unroll
                    for (int s2 = 0; s2 < 16; ++s2)
                        mstar = fmaxf(mstar, pm[p0 + (s2 << 6)]);
                    float lstar = 0.f, osum = 0.f;
#pragma unroll
                    for (int s2 = 0; s2 < 16; ++s2) {
                        int pi = p0 + (s2 << 6);
                        float e = __expf(pm[pi] - mstar);
                        lstar += pl[pi] * e;
                        osum  += po[(pi << 4) + dd] * e;
                    }
                    float outv = osum / lstar + x[(size_t)((b << 7) + c) * 4096 + col];
                    outc[(slot << 7) + c] = outv;
                    if (h == 0) feats[(size_t)((b << 7) + c) * 4096 + col] = outv;
                }
            }
            __syncthreads();
            if (!TAIL && t < 128) {
                int slot = t >> 5;
                int ow = base + slot;
                if (ow < cnt) {
                    int task = t & 31;
                    int isV = task >> 4, dd = task & 15;
                    int col = colsC[ownIdx[ow]];
                    const float* W = isV ? Wv0 : Wk0;
                    const float* oc = &outc[slot << 7];
                    int row = (h << 4) + dd;
                    float acc = 0.f;
                    for (int c2 = 0; c2 < Cn; ++c2)
                        acc += W[(row << 7) + c2] * oc[c2];
                    ushort bfv = f2bf(acc);
                    if (isV) {
                        Vbf[(size_t)(bh*16 + dd) * 4096 + col] = bfv;
                        Vls[dd*520 + (col - keybase)] = bfv;
                    } else {
                        Kbf[(size_t)((bh << 12) + col) * 16 + dd] = bfv;
                        Kls[(col - keybase)*24 + dd] = bfv;
                    }
                }
            }
            __syncthreads();
        }
    }
    if (TAIL) return;

    // ---------------- 3) MFMA flash ring r ----------------
    const int w = t >> 6, lane = t & 63;
    const int qt = w & 3, kh = w >> 2;
    const int buf = r & 1;
    if (qt * 16 < n) {
        const int lm = lane & 15, lg = lane >> 4;
        bhalf4 qf = *(const bhalf4*)&Qls[(qt*16 + lm)*24 + (lg << 2)];
        const int key0 = kh << 8;
        f32x4 sc[16];
#pragma unroll
        for (int kt = 0; kt < 16; ++kt) {
            bhalf4 kf = *(const bhalf4*)&Kls[(key0 + (kt << 4) + lm)*24 + (lg << 2)];
            f32x4 z = {0.f, 0.f, 0.f, 0.f};
            sc[kt] = __builtin_amdgcn_mfma_f32_16x16x16bf16_1k(kf, qf, z, 0, 0, 0);
        }
        float m = -1e30f;
#pragma unroll
        for (int kt = 0; kt < 16; ++kt)
            m = fmaxf(m, fmaxf(fmaxf(sc[kt][0], sc[kt][1]), fmaxf(sc[kt][2], sc[kt][3])));
        m = fmaxf(m, __shfl_xor(m, 16));
        m = fmaxf(m, __shfl_xor(m, 32));
        float lsum = 0.f;
        f32x4 oacc = {0.f, 0.f, 0.f, 0.f};
#pragma unroll
        for (int kt = 0; kt < 16; ++kt) {
            float p0 = __expf((sc[kt][0] - m) * 0.25f);
            float p1 = __expf((sc[kt][1] - m) * 0.25f);
            float p2 = __expf((sc[kt][2] - m) * 0.25f);
            float p3 = __expf((sc[kt][3] - m) * 0.25f);
            lsum += (p0 + p1) + (p2 + p3);
            bhalf4 pv;
            pv[0] = (short)f2bf(p0); pv[1] = (short)f2bf(p1);
            pv[2] = (short)f2bf(p2); pv[3] = (short)f2bf(p3);
            bhalf4 vf = *(const bhalf4*)&Vls[lm*520 + key0 + (kt << 4) + (lg << 2)];
            oacc = __builtin_amdgcn_mfma_f32_16x16x16bf16_1k(pv, vf, oacc, 0, 0, 0);
        }
        lsum += __shfl_xor(lsum, 16);
        lsum += __shfl_xor(lsum, 32);
        const int pb = ((((buf << 5) + bh) << 4) | ((sp << 1) + kh)) * 64;
        if (lg == 0) {
            pm[pb + qt*16 + lm] = m * 0.25f;
            pl[pb + qt*16 + lm] = lsum;
        }
#pragma unroll
        for (int reg = 0; reg < 4; ++reg)
            po[(pb + qt*16 + (lg << 2) + reg) * 16 + lm] = oacc[reg];
    }
}

// ---------------------------------------------------------------------------
// Epilogue 1: Va = Wv0@anchor_feats, Kn = head-normalize(Wk1@anchor_feats)
// ---------------------------------------------------------------------------
__global__ __launch_bounds__(128) void epi1(
    const float* __restrict__ feats, const float* __restrict__ Wv0,
    const float* __restrict__ Wk1, const int* __restrict__ rings,
    float* __restrict__ Va, float* __restrict__ Kn)
{
    int b = blockIdx.x;
    int i = threadIdx.x;
    int anchor = rings[0];
    __shared__ float la[128];
    __shared__ float kk2[128];
    la[i] = feats[(size_t)((b << 7) + i) * 4096 + anchor];
    __syncthreads();
    float va = 0.f, k1 = 0.f;
    for (int c = 0; c < 128; ++c) {
        va += Wv0[i * 128 + c] * la[c];
        k1 += Wk1[i * 128 + c] * la[c];
    }
    Va[b * 128 + i] = va;
    kk2[i] = k1 * k1;
    __syncthreads();
    float ss = 0.f;
    int hb = i & ~15;
    for (int d = 0; d < 16; ++d) ss += kk2[hb + d];
    Kn[b * 128 + i] = k1 * rsqrtf(ss + 1e-8f);
}

// ---------------------------------------------------------------------------
// Epilogue 2 (R11 version): reg-tiled, W^T staged in LDS once per block.
// ---------------------------------------------------------------------------
__global__ __launch_bounds__(256) void epi2(
    const float* __restrict__ x, const float* __restrict__ Wq1,
    const float* __restrict__ Va, const float* __restrict__ Kn,
    float* __restrict__ scores)
{
    __shared__ float Wt[128 * 132];
    __shared__ float lxT[128 * 36];
    const int bid = blockIdx.x, t = threadIdx.x;
    const int b = bid >> 7, col0 = (bid & 127) << 5;
    for (int idx = t; idx < 128 * 128; idx += 256) {
        int o = idx >> 7, c = idx & 127;
        Wt[c*132 + o] = Wq1[idx];
    }
    for (int idx = t; idx < 128 * 32; idx += 256) {
        int c = idx >> 5, col = idx & 31;
        lxT[c*36 + col] = x[(size_t)((b << 7) + c) * 4096 + col0 + col] + Va[(b << 7) + c];
    }
    __syncthreads();
    const int og = t & 31, colg = t >> 5;
    const int o0 = og << 2, cl0 = colg << 2;
    float acc[4][4];
#pragma unroll
    for (int i = 0; i < 4; ++i)
#pragma unroll
        for (int j = 0; j < 4; ++j) acc[i][j] = 0.f;
    for (int c = 0; c < 128; ++c) {
        f32x4 wv = *(const f32x4*)&Wt[c*132 + o0];
        f32x4 xv = *(const f32x4*)&lxT[c*36 + cl0];
#pragma unroll
        for (int i = 0; i < 4; ++i)
#pragma unroll
            for (int j = 0; j < 4; ++j) acc[i][j] += wv[i] * xv[j];
    }
    float kn4[4];
#pragma unroll
    for (int i = 0; i < 4; ++i) kn4[i] = Kn[(b << 7) + o0 + i];
    float res[4];
#pragma unroll
    for (int j = 0; j < 4; ++j) {
        float ss = acc[0][j]*acc[0][j] + acc[1][j]*acc[1][j]
                 + acc[2][j]*acc[2][j] + acc[3][j]*acc[3][j];
        ss += __shfl_xor(ss, 1);
        ss += __shfl_xor(ss, 2);
        float rs = rsqrtf(ss + 1e-8f);
        float mp = (acc[0][j]*kn4[0] + acc[1][j]*kn4[1]
                  + acc[2][j]*kn4[2] + acc[3][j]*kn4[3]) * rs;
#pragma unroll
        for (int msk = 1; msk <= 16; msk <<= 1) mp += __shfl_xor(mp, msk);
        res[j] = 0.5f + mp * (1.0f / 16.0f);
    }
    if (og == 0) {
#pragma unroll
        for (int j = 0; j < 4; ++j)
            scores[(b << 12) + col0 + cl0 + j] = res[j];
    }
}

// ---------------------------------------------------------------------------
// Launcher: 1 init + 127 rings + 1 tail + 2 epilogues = 131 launches.
// ---------------------------------------------------------------------------
extern "C" void kernel_launch(void* const* d_in, const int* in_sizes, int n_in,
                              void* d_out, int out_size, void* d_ws, size_t ws_size,
                              hipStream_t stream) {
    const float* x   = (const float*)d_in[0];
    const float* Wq0 = (const float*)d_in[1];
    const float* Wk0 = (const float*)d_in[2];
    const float* Wv0 = (const float*)d_in[3];
    const float* Wq1 = (const float*)d_in[4];
    const float* Wk1 = (const float*)d_in[5];
    const int*   rings = (const int*)d_in[6];
    const int*   rsz   = (const int*)d_in[7];

    float* feats  = (float*)d_out;                 // (B,C,F)
    float* scores = feats + Bn * Cn * Fn;          // (B,F)

    float*  ws   = (float*)d_ws;
    ushort* Q0bf = (ushort*)ws;
    ushort* Kbf  = (ushort*)(ws + OFF_K);
    ushort* Vbf  = (ushort*)(ws + OFF_V);
    float*  pm   = ws + OFF_PM;
    float*  pl   = ws + OFF_PL;
    float*  po   = ws + OFF_PO;
    float*  Va   = ws + OFF_VA;
    float*  Kn   = ws + OFF_KN;

    initQKV<<<256, 512, 0, stream>>>(x, Wq0, Wk0, Wv0, Q0bf, Kbf, Vbf);

    for (int r = 0; r < NRINGS; ++r) {
        fusedRing<false><<<256, 512, 0, stream>>>(
            x, Wk0, Wv0, rings, rsz, Q0bf, Kbf, Vbf, pm, pl, po, feats, r);
    }
    fusedRing<true><<<256, 512, 0, stream>>>(
        x, Wk0, Wv0, rings, rsz, Q0bf, Kbf, Vbf, pm, pl, po, feats, NRINGS);

    epi1<<<Bn, 128, 0, stream>>>(feats, Wv0, Wk1, rings, Va, Kn);
    epi2<<<512, 256, 0, stream>>>(x, Wq1, Va, Kn, scores);
}

// Round 13
// 1611.780 us; speedup vs baseline: 2.4005x; 1.0767x over previous
//
#include <hip/hip_runtime.h>
#include <hip/hip_bf16.h>

// (B,C,H,G) = (4,128,8,64); F=4096, DH=16, 127 rings.
// Ring r columns are arithmetic: col_j = 63*(i0+j)+r, i0=max(0,r-63),
// j in [0, n) with n = min(r,63)-max(0,r-63)+1  (matches _build_rings).
#define Bn 4
#define Cn 128
#define Fn 4096
#define NRINGS 127

typedef short bhalf4 __attribute__((ext_vector_type(4)));
typedef float f32x4  __attribute__((ext_vector_type(4)));

// workspace offsets (float-slot units)
#define OFF_K   1048576
#define OFF_V   2097152
#define OFF_PM  3145728   // 2 buf * 32 bh * 16 sl * 64 q = 65536
#define OFF_PL  3211264   // 65536
#define OFF_PO  3276800   // * 16 d = 1048576
#define OFF_VA  4325376
#define OFF_KN  4325888

__device__ __forceinline__ ushort f2bf(float f) {
    __hip_bfloat16 h = __float2bfloat16(f);
    return *reinterpret_cast<ushort*>(&h);
}

__device__ __forceinline__ int ringN(int r) {
    return (r < 64 ? r : 63) - (r > 63 ? r - 63 : 0) + 1;
}

// ---------------------------------------------------------------------------
// init (proven 47 us): Q0bf/Kbf rows [bh][col][16] bf16; Vbf transposed
// [bh][d][col] bf16. W staged in LDS (+1-padded) per 32-c chunk.
// ---------------------------------------------------------------------------
__global__ __launch_bounds__(512, 2) void initQKV(
    const float* __restrict__ x, const float* __restrict__ Wq0,
    const float* __restrict__ Wk0, const float* __restrict__ Wv0,
    ushort* __restrict__ Q0bf, ushort* __restrict__ Kbf, ushort* __restrict__ Vbf)
{
    __shared__ float xs[Cn * 64];
    __shared__ float Wls[3 * 128 * 33];
    const int wg = blockIdx.x, t = threadIdx.x;
    const int b = wg >> 6, n0 = (wg & 63) << 6;
    for (int idx = t; idx < Cn * 64; idx += 512) {
        int c = idx >> 6, j = idx & 63;
        xs[idx] = x[(size_t)((b << 7) + c) * 4096 + n0 + j];
    }
    const int o = t & 127, j0 = (t >> 7) << 4;
    float aq[16], ak[16], av[16];
#pragma unroll
    for (int k = 0; k < 16; ++k) { aq[k] = 0.f; ak[k] = 0.f; av[k] = 0.f; }
    for (int cc = 0; cc < 128; cc += 32) {
        __syncthreads();
        for (int idx = t; idx < 128 * 32; idx += 512) {
            int oo = idx >> 5, jj = idx & 31;
            Wls[oo * 33 + jj]                = Wq0[(oo << 7) + cc + jj];
            Wls[128 * 33 + oo * 33 + jj]     = Wk0[(oo << 7) + cc + jj];
            Wls[2 * 128 * 33 + oo * 33 + jj] = Wv0[(oo << 7) + cc + jj];
        }
        __syncthreads();
        for (int c2 = 0; c2 < 32; ++c2) {
            float wq = Wls[o * 33 + c2];
            float wk = Wls[128 * 33 + o * 33 + c2];
            float wv = Wls[2 * 128 * 33 + o * 33 + c2];
            const f32x4* xr4 = (const f32x4*)&xs[((cc + c2) << 6) + j0];
#pragma unroll
            for (int k4 = 0; k4 < 4; ++k4) {
                f32x4 xv = xr4[k4];
#pragma unroll
                for (int e = 0; e < 4; ++e) {
                    int k = (k4 << 2) + e;
                    aq[k] += wq * xv[e]; ak[k] += wk * xv[e]; av[k] += wv * xv[e];
                }
            }
        }
    }
    const int h = o >> 4, d = o & 15;
    const int bh = (b << 3) + h;
#pragma unroll
    for (int k = 0; k < 16; ++k) {
        int col = n0 + j0 + k;
        size_t qi = (size_t)(bh * 4096 + col) * 16 + d;
        Q0bf[qi] = f2bf(aq[k]);
        Kbf[qi]  = f2bf(ak[k]);
    }
    uint vv[8];
#pragma unroll
    for (int k2 = 0; k2 < 8; ++k2)
        vv[k2] = (uint)f2bf(av[2*k2]) | ((uint)f2bf(av[2*k2+1]) << 16);
    uint4* dst = (uint4*)&Vbf[(size_t)(bh * 16 + d) * 4096 + n0 + j0];
    dst[0] = make_uint4(vv[0], vv[1], vv[2], vv[3]);
    dst[1] = make_uint4(vv[4], vv[5], vv[6], vv[7]);
}

// ---------------------------------------------------------------------------
// Fused per-ring kernel, overlap-restructured. WG (b,h,sp of 512 keys).
//   - stage K/V/Q global loads issued into REGISTERS at kernel top
//   - combine-merge ring r-1 (arithmetic cols, contiguous owned j-range)
//     runs while stage loads are in flight; writes outc (LDS) + feats
//   - staged regs -> LDS; ONE barrier
//   - GEMV+patch (single pass, 16 col-slots x 32 tasks); ONE barrier
//   - MFMA flash ring r; partial stores in proven R5 layout
// ---------------------------------------------------------------------------
template<bool TAIL>
__global__ __launch_bounds__(512, 2) void fusedRing(
    const float* __restrict__ x, const float* __restrict__ Wk0,
    const float* __restrict__ Wv0, const ushort* __restrict__ Q0bf,
    ushort* __restrict__ Kbf, ushort* __restrict__ Vbf,
    float* __restrict__ pm, float* __restrict__ pl, float* __restrict__ po,
    float* __restrict__ feats, int r)
{
    __shared__ ushort Kls[512 * 24];   // 24 KB, rows 48B (2-way banks)
    __shared__ ushort Vls[16 * 520];   // 16.3 KB, V^T rows, stride 1040B
    __shared__ ushort Qls[64 * 24];    // 3 KB
    __shared__ float  outc[12 * 128];  // cnt <= ceil(512/63)=9 owned cols

    const int t = threadIdx.x, wgid = blockIdx.x;
    const int b = wgid >> 6, h = (wgid >> 3) & 7, sp = wgid & 7;
    const int bh = (b << 3) + h;
    const int keybase = sp << 9;

    const int n   = TAIL ? 0 : ringN(r);
    const int rp  = r - 1;
    const int np  = (r > 0) ? ringN(rp) : 0;
    const int i0p = (r > 0) ? (rp > 63 ? rp - 63 : 0) : 0;

    // owned j-range of prev ring within [keybase, keybase+512)
    int jlo = 0, cnt = 0;
    if (r > 0) {
        int A = keybase - rp;
        int mlo = (A > 0) ? (A + 62) / 63 : 0;           // min (i0p+j)
        int mhiN = keybase + 511 - rp;
        int mhi = (mhiN < 0) ? -1 : mhiN / 63;           // max (i0p+j)
        int jl = mlo - i0p;      if (jl < 0) jl = 0;
        int jh = mhi - i0p;      if (jh > np - 1) jh = np - 1;
        jlo = jl;
        cnt = (jh >= jl) ? (jh - jl + 1) : 0;
    }

    // ---- issue staging loads into registers (latency hides under merge) ----
    uint4 k0q, k1q, v0q, v1q, qreg;
    if (!TAIL) {
        const uint4* ks = (const uint4*)(Kbf + (size_t)((bh << 12) + keybase + t) * 16);
        k0q = ks[0]; k1q = ks[1];
        int vdd = t >> 5, vcc = t & 31;
        const uint4* vs = (const uint4*)(Vbf + (size_t)(bh * 16 + vdd) * 4096
                                         + keybase + (vcc << 4));
        v0q = vs[0]; v1q = vs[1];
        if (t < 128) {
            int q = t >> 1, half = t & 1;
            int i0F = (r > 63) ? r - 63 : 0;
            int cq = (q < n) ? (63 * (i0F + q) + r) : 0;
            qreg = *(const uint4*)(Q0bf + (size_t)((bh << 12) + cq) * 16 + half * 8);
        }
    }

    // ---- combine-merge ring r-1 (no prior barrier needed) ----
    if (r > 0 && cnt > 0) {
        const int bufp = rp & 1;
        const int slot = t >> 7, c = t & 127;
        const int hh = c >> 4, dd = c & 15;
        for (int base = 0; base < cnt; base += 4) {
            int ow = base + slot;
            if (ow < cnt) {
                int j = jlo + ow;
                int col = 63 * (i0p + j) + rp;
                int p0 = ((bufp << 5) + (b << 3) + hh) * 1024 + j;
                float mstar = -1e30f;
#pragma unroll
                for (int s2 = 0; s2 < 16; ++s2)
                    mstar = fmaxf(mstar, pm[p0 + (s2 << 6)]);
                float lstar = 0.f, osum = 0.f;
#pragma unroll
                for (int s2 = 0; s2 < 16; ++s2) {
                    int pi = p0 + (s2 << 6);
                    float e = __expf(pm[pi] - mstar);
                    lstar += pl[pi] * e;
                    osum  += po[(pi << 4) + dd] * e;
                }
                float outv = osum / lstar + x[(size_t)((b << 7) + c) * 4096 + col];
                outc[ow * 128 + c] = outv;
                if (h == 0) feats[(size_t)((b << 7) + c) * 4096 + col] = outv;
            }
        }
    }

    // ---- staged regs -> LDS ----
    if (!TAIL) {
        *(uint4*)&Kls[t * 24]     = k0q;
        *(uint4*)&Kls[t * 24 + 8] = k1q;
        int vdd = t >> 5, vcc = t & 31;
        *(uint4*)&Vls[vdd * 520 + (vcc << 4)]     = v0q;
        *(uint4*)&Vls[vdd * 520 + (vcc << 4) + 8] = v1q;
        if (t < 128) {
            int q = t >> 1, half = t & 1;
            *(uint4*)&Qls[q * 24 + half * 8] = qreg;
        }
    }
    __syncthreads();   // BAR1: outc + staged LDS visible

    // ---- GEMV + patch (single pass: 16 col-slots x 32 tasks) ----
    if (!TAIL && cnt > 0) {
        int slot = t >> 5, task = t & 31;
        if (slot < cnt) {
            int j = jlo + slot;
            int col = 63 * (i0p + j) + rp;
            int isV = task >> 4, dd = task & 15;
            int row = (h << 4) + dd;
            const float* W = isV ? Wv0 : Wk0;
            const float* oc = &outc[slot * 128];
            float acc = 0.f;
            for (int c2 = 0; c2 < Cn; ++c2)
                acc += W[(row << 7) + c2] * oc[c2];
            ushort bfv = f2bf(acc);
            if (isV) {
                Vbf[(size_t)(bh * 16 + dd) * 4096 + col] = bfv;
                Vls[dd * 520 + (col - keybase)] = bfv;
            } else {
                Kbf[(size_t)((bh << 12) + col) * 16 + dd] = bfv;
                Kls[(col - keybase) * 24 + dd] = bfv;
            }
        }
    }
    if (TAIL) return;
    __syncthreads();   // BAR2: patches visible

    // ---- MFMA flash ring r ----
    const int w = t >> 6, lane = t & 63;
    const int qt = w & 3, kh = w >> 2;
    const int buf = r & 1;
    if (qt * 16 < n) {
        const int lm = lane & 15, lg = lane >> 4;
        bhalf4 qf = *(const bhalf4*)&Qls[(qt * 16 + lm) * 24 + (lg << 2)];
        const int key0 = kh << 8;
        f32x4 sc[16];
#pragma unroll
        for (int kt = 0; kt < 16; ++kt) {
            bhalf4 kf = *(const bhalf4*)&Kls[(key0 + (kt << 4) + lm) * 24 + (lg << 2)];
            f32x4 z = {0.f, 0.f, 0.f, 0.f};
            sc[kt] = __builtin_amdgcn_mfma_f32_16x16x16bf16_1k(kf, qf, z, 0, 0, 0);
        }
        float m = -1e30f;
#pragma unroll
        for (int kt = 0; kt < 16; ++kt)
            m = fmaxf(m, fmaxf(fmaxf(sc[kt][0], sc[kt][1]), fmaxf(sc[kt][2], sc[kt][3])));
        m = fmaxf(m, __shfl_xor(m, 16));
        m = fmaxf(m, __shfl_xor(m, 32));
        float lsum = 0.f;
        f32x4 oacc = {0.f, 0.f, 0.f, 0.f};
#pragma unroll
        for (int kt = 0; kt < 16; ++kt) {
            float p0 = __expf((sc[kt][0] - m) * 0.25f);
            float p1 = __expf((sc[kt][1] - m) * 0.25f);
            float p2 = __expf((sc[kt][2] - m) * 0.25f);
            float p3 = __expf((sc[kt][3] - m) * 0.25f);
            lsum += (p0 + p1) + (p2 + p3);
            bhalf4 pv;
            pv[0] = (short)f2bf(p0); pv[1] = (short)f2bf(p1);
            pv[2] = (short)f2bf(p2); pv[3] = (short)f2bf(p3);
            bhalf4 vf = *(const bhalf4*)&Vls[lm * 520 + key0 + (kt << 4) + (lg << 2)];
            oacc = __builtin_amdgcn_mfma_f32_16x16x16bf16_1k(pv, vf, oacc, 0, 0, 0);
        }
        lsum += __shfl_xor(lsum, 16);
        lsum += __shfl_xor(lsum, 32);
        const int pb = ((((buf << 5) + bh) << 4) | ((sp << 1) + kh)) * 64;
        if (lg == 0) {
            pm[pb + qt * 16 + lm] = m * 0.25f;
            pl[pb + qt * 16 + lm] = lsum;
        }
#pragma unroll
        for (int reg = 0; reg < 4; ++reg)
            po[(pb + qt * 16 + (lg << 2) + reg) * 16 + lm] = oacc[reg];
    }
}

// ---------------------------------------------------------------------------
// Epilogue 1: Va = Wv0@anchor_feats, Kn = head-normalize(Wk1@anchor_feats)
// ---------------------------------------------------------------------------
__global__ __launch_bounds__(128) void epi1(
    const float* __restrict__ feats, const float* __restrict__ Wv0,
    const float* __restrict__ Wk1, const int* __restrict__ rings,
    float* __restrict__ Va, float* __restrict__ Kn)
{
    int b = blockIdx.x;
    int i = threadIdx.x;
    int anchor = rings[0];
    __shared__ float la[128];
    __shared__ float kk2[128];
    la[i] = feats[(size_t)((b << 7) + i) * 4096 + anchor];
    __syncthreads();
    float va = 0.f, k1 = 0.f;
    for (int c = 0; c < 128; ++c) {
        va += Wv0[i * 128 + c] * la[c];
        k1 += Wk1[i * 128 + c] * la[c];
    }
    Va[b * 128 + i] = va;
    kk2[i] = k1 * k1;
    __syncthreads();
    float ss = 0.f;
    int hb = i & ~15;
    for (int d = 0; d < 16; ++d) ss += kk2[hb + d];
    Kn[b * 128 + i] = k1 * rsqrtf(ss + 1e-8f);
}

// ---------------------------------------------------------------------------
// Epilogue 2: reg-tiled, W^T staged in LDS once per block.
// ---------------------------------------------------------------------------
__global__ __launch_bounds__(256) void epi2(
    const float* __restrict__ x, const float* __restrict__ Wq1,
    const float* __restrict__ Va, const float* __restrict__ Kn,
    float* __restrict__ scores)
{
    __shared__ float Wt[128 * 132];
    __shared__ float lxT[128 * 36];
    const int bid = blockIdx.x, t = threadIdx.x;
    const int b = bid >> 7, col0 = (bid & 127) << 5;
    for (int idx = t; idx < 128 * 128; idx += 256) {
        int o = idx >> 7, c = idx & 127;
        Wt[c*132 + o] = Wq1[idx];
    }
    for (int idx = t; idx < 128 * 32; idx += 256) {
        int c = idx >> 5, col = idx & 31;
        lxT[c*36 + col] = x[(size_t)((b << 7) + c) * 4096 + col0 + col] + Va[(b << 7) + c];
    }
    __syncthreads();
    const int og = t & 31, colg = t >> 5;
    const int o0 = og << 2, cl0 = colg << 2;
    float acc[4][4];
#pragma unroll
    for (int i = 0; i < 4; ++i)
#pragma unroll
        for (int j = 0; j < 4; ++j) acc[i][j] = 0.f;
    for (int c = 0; c < 128; ++c) {
        f32x4 wv = *(const f32x4*)&Wt[c*132 + o0];
        f32x4 xv = *(const f32x4*)&lxT[c*36 + cl0];
#pragma unroll
        for (int i = 0; i < 4; ++i)
#pragma unroll
            for (int j = 0; j < 4; ++j) acc[i][j] += wv[i] * xv[j];
    }
    float kn4[4];
#pragma unroll
    for (int i = 0; i < 4; ++i) kn4[i] = Kn[(b << 7) + o0 + i];
    float res[4];
#pragma unroll
    for (int j = 0; j < 4; ++j) {
        float ss = acc[0][j]*acc[0][j] + acc[1][j]*acc[1][j]
                 + acc[2][j]*acc[2][j] + acc[3][j]*acc[3][j];
        ss += __shfl_xor(ss, 1);
        ss += __shfl_xor(ss, 2);
        float rs = rsqrtf(ss + 1e-8f);
        float mp = (acc[0][j]*kn4[0] + acc[1][j]*kn4[1]
                  + acc[2][j]*kn4[2] + acc[3][j]*kn4[3]) * rs;
#pragma unroll
        for (int msk = 1; msk <= 16; msk <<= 1) mp += __shfl_xor(mp, msk);
        res[j] = 0.5f + mp * (1.0f / 16.0f);
    }
    if (og == 0) {
#pragma unroll
        for (int j = 0; j < 4; ++j)
            scores[(b << 12) + col0 + cl0 + j] = res[j];
    }
}

// ---------------------------------------------------------------------------
// Launcher: 1 init + 127 rings + 1 tail + 2 epilogues = 131 launches.
// ---------------------------------------------------------------------------
extern "C" void kernel_launch(void* const* d_in, const int* in_sizes, int n_in,
                              void* d_out, int out_size, void* d_ws, size_t ws_size,
                              hipStream_t stream) {
    const float* x   = (const float*)d_in[0];
    const float* Wq0 = (const float*)d_in[1];
    const float* Wk0 = (const float*)d_in[2];
    const float* Wv0 = (const float*)d_in[3];
    const float* Wq1 = (const float*)d_in[4];
    const float* Wk1 = (const float*)d_in[5];
    const int*   rings = (const int*)d_in[6];

    float* feats  = (float*)d_out;                 // (B,C,F)
    float* scores = feats + Bn * Cn * Fn;          // (B,F)

    float*  ws   = (float*)d_ws;
    ushort* Q0bf = (ushort*)ws;
    ushort* Kbf  = (ushort*)(ws + OFF_K);
    ushort* Vbf  = (ushort*)(ws + OFF_V);
    float*  pm   = ws + OFF_PM;
    float*  pl   = ws + OFF_PL;
    float*  po   = ws + OFF_PO;
    float*  Va   = ws + OFF_VA;
    float*  Kn   = ws + OFF_KN;

    initQKV<<<256, 512, 0, stream>>>(x, Wq0, Wk0, Wv0, Q0bf, Kbf, Vbf);

    for (int r = 0; r < NRINGS; ++r) {
        fusedRing<false><<<256, 512, 0, stream>>>(
            x, Wk0, Wv0, Q0bf, Kbf, Vbf, pm, pl, po, feats, r);
    }
    fusedRing<true><<<256, 512, 0, stream>>>(
        x, Wk0, Wv0, Q0bf, Kbf, Vbf, pm, pl, po, feats, NRINGS);

    epi1<<<Bn, 128, 0, stream>>>(feats, Wv0, Wk1, rings, Va, Kn);
    epi2<<<512, 256, 0, stream>>>(x, Wq1, Va, Kn, scores);
}